// Round 6
// baseline (922.510 us; speedup 1.0000x reference)
//
#include <hip/hip_runtime.h>
#include <math.h>

// Problem constants (DeformConv_68109591380935) — ALL TENSORS FLOAT32
#define BN_    4
#define CHI_   256
#define CHO_   256
#define HH_    96
#define WW_    96
#define HW_    (HH_*WW_)        // 9216
#define KK_    9
#define CK_    (CHI_*KK_)       // 2304
#define NRED_  (BN_*HW_)        // 36864 samples per BN channel
#define BN_EPS_ 1e-5f

#define TPX_   64
#define KC_    64               // fused-path K-chunk
#define PITCH_ 72               // fused-path LDS pitch

// offset_mfma tiling
#define OKC_    96
#define OPITCH_ 104

typedef short short8 __attribute__((ext_vector_type(8)));
typedef float f32x4  __attribute__((ext_vector_type(4)));

__device__ __forceinline__ unsigned short f2bf(float v) {
    union { float f; unsigned u; } c; c.f = v;
    unsigned lsb = (c.u >> 16) & 1u;
    c.u += 0x7fffu + lsb;
    return (unsigned short)(c.u >> 16);
}

// bilinear gather of one col element, given meta arrays indexed [k*64 + i]
__device__ __forceinline__ float gather_one(
    const float* __restrict__ xb, const float* s_py, const float* s_px,
    const float* s_mask, int jg, int i)
{
    int c = (jg * 7282) >> 16;            // jg/9 (exact for jg<2304)
    int k = jg - 9 * c;
    float py = s_py[k * 64 + i], px = s_px[k * 64 + i];
    float y0f = floorf(py), x0f = floorf(px);
    float ly = py - y0f, lx = px - x0f;
    int y0 = (int)y0f, x0 = (int)x0f;
    float vy0 = ((unsigned)y0       < HH_) ? 1.f : 0.f;
    float vy1 = ((unsigned)(y0 + 1) < HH_) ? 1.f : 0.f;
    float vx0 = ((unsigned)x0       < WW_) ? 1.f : 0.f;
    float vx1 = ((unsigned)(x0 + 1) < WW_) ? 1.f : 0.f;
    int yc0 = min(max(y0, 0), HH_ - 1), yc1 = min(max(y0 + 1, 0), HH_ - 1);
    int xc0 = min(max(x0, 0), WW_ - 1), xc1 = min(max(x0 + 1, 0), WW_ - 1);
    const float* img = xb + (size_t)c * HW_;
    float f00 = img[yc0 * WW_ + xc0];
    float f01 = img[yc0 * WW_ + xc1];
    float f10 = img[yc1 * WW_ + xc0];
    float f11 = img[yc1 * WW_ + xc1];
    float wy0 = 1.f - ly, wx0 = 1.f - lx;
    float v = f00 * (wy0 * wx0 * vy0 * vx0) + f01 * (wy0 * lx * vy0 * vx1)
            + f10 * (ly  * wx0 * vy1 * vx0) + f11 * (ly  * lx * vy1 * vx1);
    return v * s_mask[k * 64 + i];
}

// ---------------------------------------------------------------------------
// Kernel 0: f32 -> bf16 convert
// ---------------------------------------------------------------------------
__global__ __launch_bounds__(256) void w2b(
    const float* __restrict__ w, unsigned short* __restrict__ wb)
{
    int idx = blockIdx.x * 256 + threadIdx.x;
    wb[idx] = f2bf(w[idx]);
}

// ---------------------------------------------------------------------------
// Kernel 1: offset conv as MFMA GEMM (32 oc x 64 px blocks)
// ---------------------------------------------------------------------------
__global__ __launch_bounds__(256) void offset_mfma(
    const float* __restrict__ x, const unsigned short* __restrict__ wob,
    const float* __restrict__ bo, float* __restrict__ om)
{
    __shared__ __align__(16) unsigned short s_w[32 * OPITCH_];
    __shared__ __align__(16) unsigned short s_cols[TPX_ * OPITCH_];

    const int t = threadIdx.x;
    const int pixtile = blockIdx.x % (HW_ / TPX_);
    const int b       = blockIdx.x / (HW_ / TPX_);
    const int p0 = pixtile * TPX_;

    const int lane = t & 63, wave = t >> 6;
    const int quad = lane >> 4, l15 = lane & 15;

    const int i   = t & 63;
    const int jlb = (t >> 6) * 24;
    const int p   = p0 + i;
    const int h   = p / WW_, w = p % WW_;
    const float* xb = x + (size_t)b * CHI_ * HW_;

    f32x4 acc[2];
    acc[0] = (f32x4){0.f,0.f,0.f,0.f};
    acc[1] = (f32x4){0.f,0.f,0.f,0.f};

    for (int kc = 0; kc < CK_ / OKC_; kc++) {
        const int j0 = kc * OKC_;
        if (kc) __syncthreads();
#pragma unroll
        for (int n = 0; n < 3; n++) {
            int e = t + n * 256;
            int ocl = e / 24, kq = e % 24;
            uint2 v = make_uint2(0u, 0u);
            if (ocl < 27)
                v = *reinterpret_cast<const uint2*>(wob + (size_t)ocl * CK_ + j0 + kq * 4);
            *reinterpret_cast<uint2*>(&s_w[ocl * OPITCH_ + kq * 4]) = v;
        }
        union { unsigned short s[24]; uint4 q[3]; } pk;
#pragma unroll
        for (int m = 0; m < 24; m++) {
            int jg = j0 + jlb + m;
            int c  = (jg * 7282) >> 16;
            int k  = jg - 9 * c;
            int yy = h + k / 3 - 1, xx = w + k % 3 - 1;
            bool ok = ((unsigned)yy < HH_) & ((unsigned)xx < WW_);
            float v = ok ? xb[(size_t)c * HW_ + yy * WW_ + xx] : 0.f;
            pk.s[m] = f2bf(v);
        }
        {
            uint4* dst = reinterpret_cast<uint4*>(&s_cols[i * OPITCH_ + jlb]);
            dst[0] = pk.q[0]; dst[1] = pk.q[1]; dst[2] = pk.q[2];
        }
        __syncthreads();
#pragma unroll
        for (int ks = 0; ks < OKC_ / 32; ks++) {
            short8 a0 = *reinterpret_cast<const short8*>(
                &s_w[(l15) * OPITCH_ + ks * 32 + quad * 8]);
            short8 a1 = *reinterpret_cast<const short8*>(
                &s_w[(16 + l15) * OPITCH_ + ks * 32 + quad * 8]);
            short8 b0 = *reinterpret_cast<const short8*>(
                &s_cols[(wave * 16 + l15) * OPITCH_ + ks * 32 + quad * 8]);
            acc[0] = __builtin_amdgcn_mfma_f32_16x16x32_bf16(a0, b0, acc[0], 0, 0, 0);
            acc[1] = __builtin_amdgcn_mfma_f32_16x16x32_bf16(a1, b0, acc[1], 0, 0, 0);
        }
    }
#pragma unroll
    for (int mt = 0; mt < 2; mt++) {
#pragma unroll
        for (int r = 0; r < 4; r++) {
            int oc = mt * 16 + quad * 4 + r;
            if (oc < 27) {
                int pix = p0 + wave * 16 + l15;
                om[((size_t)b * 27 + oc) * HW_ + pix] = acc[mt][r] + bo[oc];
            }
        }
    }
}

// ---------------------------------------------------------------------------
// Kernel 2a: standalone gather -> cols[b][px][k] bf16 (170 MB), huge grid.
//   Block = (b, px-tile of 64, k-slice of 256). lane = pixel (coalesced x).
// ---------------------------------------------------------------------------
__global__ __launch_bounds__(256) void gather_cols(
    const float* __restrict__ x, const float* __restrict__ om,
    unsigned short* __restrict__ colsb)
{
    __shared__ float s_py[KK_ * 64], s_px[KK_ * 64], s_mask[KK_ * 64];

    const int t = threadIdx.x;
    const int kslice  = blockIdx.x % 9;
    const int pixtile = (blockIdx.x / 9) % (HW_ / 64);
    const int b       = blockIdx.x / (9 * (HW_ / 64));
    const int p0 = pixtile * 64;

    for (int e = t; e < KK_ * 64; e += 256) {
        int k = e / 64, i = e % 64;
        int p = p0 + i;
        int h = p / WW_, w = p % WW_;
        const float* omb = om + ((size_t)b * 27) * HW_ + p;
        float dy = omb[(2 * k) * HW_];
        float dx = omb[(2 * k + 1) * HW_];
        float m  = omb[(18 + k) * HW_];
        s_py[e]   = dy + (float)(h + k / 3 - 1);
        s_px[e]   = dx + (float)(w + (k % 3) - 1);
        s_mask[e] = 1.f / (1.f + __expf(-m));
    }
    __syncthreads();

    const int i   = t & 63;                       // pixel
    const int jg0 = kslice * 256 + (t >> 6) * 64; // this thread's 64 k's
    const float* xb = x + (size_t)b * CHI_ * HW_;
    unsigned short* dst = colsb + ((size_t)b * HW_ + p0 + i) * CK_ + jg0;

#pragma unroll 1
    for (int g = 0; g < 8; g++) {
        union { unsigned short s[8]; uint4 q; } pk;
#pragma unroll
        for (int m = 0; m < 8; m++)
            pk.s[m] = f2bf(gather_one(xb, s_py, s_px, s_mask, jg0 + g * 8 + m, i));
        *reinterpret_cast<uint4*>(dst + g * 8) = pk.q;
    }
}

// ---------------------------------------------------------------------------
// Kernel 2b: GEMM from materialized cols. NO LDS, NO barriers.
//   Block = 4 waves; wave = 64 oc x 64 px tile. A and B fragments are direct
//   16B global loads (lane l15 = row, quad*8 = k offset -> contiguous uint4).
// ---------------------------------------------------------------------------
__global__ __launch_bounds__(256) void gemm_cols(
    const unsigned short* __restrict__ colsb, const unsigned short* __restrict__ wb,
    const float* __restrict__ bconv, float* __restrict__ outb)
{
    const int t = threadIdx.x;
    const int pixtile = blockIdx.x % (HW_ / TPX_);
    const int b       = blockIdx.x / (HW_ / TPX_);
    const int p0 = pixtile * TPX_;
    const int lane = t & 63, wave = t >> 6;
    const int quad = lane >> 4, l15 = lane & 15;
    const int ocb  = wave * 64;

    f32x4 acc[4][4];
#pragma unroll
    for (int m = 0; m < 4; m++)
#pragma unroll
        for (int n = 0; n < 4; n++)
            acc[m][n] = (f32x4){0.f, 0.f, 0.f, 0.f};

    const unsigned short* wbase = wb + (size_t)(ocb + l15) * CK_;
    const unsigned short* cbase = colsb + ((size_t)b * HW_ + p0 + l15) * CK_;

#pragma unroll 1
    for (int k0 = 0; k0 < CK_; k0 += 32) {
        short8 afr[4], bfr[4];
#pragma unroll
        for (int m = 0; m < 4; m++)
            afr[m] = *reinterpret_cast<const short8*>(
                wbase + (size_t)m * 16 * CK_ + k0 + quad * 8);
#pragma unroll
        for (int n = 0; n < 4; n++)
            bfr[n] = *reinterpret_cast<const short8*>(
                cbase + (size_t)n * 16 * CK_ + k0 + quad * 8);
#pragma unroll
        for (int m = 0; m < 4; m++)
#pragma unroll
            for (int n = 0; n < 4; n++)
                acc[m][n] = __builtin_amdgcn_mfma_f32_16x16x32_bf16(
                    afr[m], bfr[n], acc[m][n], 0, 0, 0);
    }

#pragma unroll
    for (int m = 0; m < 4; m++)
#pragma unroll
        for (int n = 0; n < 4; n++)
#pragma unroll
            for (int r = 0; r < 4; r++) {
                int oc  = ocb + m * 16 + quad * 4 + r;
                int pix = p0 + n * 16 + l15;
                outb[((size_t)b * CHO_ + oc) * HW_ + pix] = acc[m][n][r] + bconv[oc];
            }
}

// ---------------------------------------------------------------------------
// Kernel 2-fallback: fused gather+GEMM (R5 version), used if ws too small
// ---------------------------------------------------------------------------
__global__ __launch_bounds__(256) void deform_fused(
    const float* __restrict__ x, const float* __restrict__ om,
    const unsigned short* __restrict__ wb, const float* __restrict__ bconv,
    float* __restrict__ outb)
{
    __shared__ __align__(16) unsigned short s_w[CHO_ * PITCH_];
    __shared__ __align__(16) unsigned short s_cols[TPX_ * PITCH_];
    __shared__ float s_py[KK_ * TPX_], s_px[KK_ * TPX_], s_mask[KK_ * TPX_];

    const int t = threadIdx.x;
    const int pixtile = blockIdx.x % (HW_ / TPX_);
    const int b       = blockIdx.x / (HW_ / TPX_);
    const int p0 = pixtile * TPX_;

    for (int e = t; e < KK_ * TPX_; e += 256) {
        int k = e / TPX_, i = e % TPX_;
        int p = p0 + i;
        int h = p / WW_, w = p % WW_;
        const float* omb = om + ((size_t)b * 27) * HW_ + p;
        float dy = omb[(2 * k) * HW_];
        float dx = omb[(2 * k + 1) * HW_];
        float m  = omb[(18 + k) * HW_];
        s_py[e]   = dy + (float)(h + k / 3 - 1);
        s_px[e]   = dx + (float)(w + (k % 3) - 1);
        s_mask[e] = 1.f / (1.f + __expf(-m));
    }

    const int lane = t & 63, wave = t >> 6;
    const int quad = lane >> 4, l15 = lane & 15;
    const int ib   = t & 63;
    const int jlb  = (t >> 6) << 4;

    f32x4 acc[4][4];
#pragma unroll
    for (int m = 0; m < 4; m++)
#pragma unroll
        for (int n = 0; n < 4; n++)
            acc[m][n] = (f32x4){0.f, 0.f, 0.f, 0.f};

    const float* xb = x + (size_t)b * CHI_ * HW_;
    __syncthreads();

    for (int kc = 0; kc < CK_ / KC_; kc++) {
        const int j0 = kc * KC_;
        if (kc) __syncthreads();
#pragma unroll
        for (int n = 0; n < 8; n++) {
            int e = t + n * 256;
            int ocl = e >> 3, ko = e & 7;
            uint4 v = *reinterpret_cast<const uint4*>(
                wb + (size_t)ocl * CK_ + j0 + ko * 8);
            *reinterpret_cast<uint4*>(&s_w[ocl * PITCH_ + ko * 8]) = v;
        }
        union { unsigned short s[16]; uint4 q[2]; } pk;
#pragma unroll
        for (int m = 0; m < 16; m++)
            pk.s[m] = f2bf(gather_one(xb, s_py, s_px, s_mask, j0 + jlb + m, ib));
        {
            uint4* dst = reinterpret_cast<uint4*>(&s_cols[ib * PITCH_ + jlb]);
            dst[0] = pk.q[0]; dst[1] = pk.q[1];
        }
        __syncthreads();
#pragma unroll
        for (int ks = 0; ks < KC_ / 32; ks++) {
            short8 afr[4], bfr[4];
#pragma unroll
            for (int m = 0; m < 4; m++)
                afr[m] = *reinterpret_cast<const short8*>(
                    &s_w[(wave * 64 + m * 16 + l15) * PITCH_ + ks * 32 + quad * 8]);
#pragma unroll
            for (int n = 0; n < 4; n++)
                bfr[n] = *reinterpret_cast<const short8*>(
                    &s_cols[(n * 16 + l15) * PITCH_ + ks * 32 + quad * 8]);
#pragma unroll
            for (int m = 0; m < 4; m++)
#pragma unroll
                for (int n = 0; n < 4; n++)
                    acc[m][n] = __builtin_amdgcn_mfma_f32_16x16x32_bf16(
                        afr[m], bfr[n], acc[m][n], 0, 0, 0);
        }
    }
#pragma unroll
    for (int m = 0; m < 4; m++)
#pragma unroll
        for (int n = 0; n < 4; n++)
#pragma unroll
            for (int r = 0; r < 4; r++) {
                int oc  = wave * 64 + m * 16 + quad * 4 + r;
                int pix = p0 + n * 16 + l15;
                outb[((size_t)b * CHO_ + oc) * HW_ + pix] = acc[m][n][r] + bconv[oc];
            }
}

// ---------------------------------------------------------------------------
// Kernel 3: BN statistics
// ---------------------------------------------------------------------------
__global__ __launch_bounds__(256) void bn_stats(
    const float* __restrict__ outb, float* __restrict__ stats)
{
    int o = blockIdx.x, t = threadIdx.x;
    float s = 0.f, s2 = 0.f;
    for (int b = 0; b < BN_; b++) {
        const float* base = outb + ((size_t)b * CHO_ + o) * HW_;
        for (int p = t; p < HW_; p += 256) {
            float v = base[p];
            s += v; s2 += v * v;
        }
    }
#pragma unroll
    for (int off = 32; off > 0; off >>= 1) {
        s  += __shfl_down(s,  off, 64);
        s2 += __shfl_down(s2, off, 64);
    }
    __shared__ float rs[4], rs2[4];
    int lane = t & 63, wv = t >> 6;
    if (lane == 0) { rs[wv] = s; rs2[wv] = s2; }
    __syncthreads();
    if (t == 0) {
        stats[o]        = rs[0] + rs[1] + rs[2] + rs[3];
        stats[CHO_ + o] = rs2[0] + rs2[1] + rs2[2] + rs2[3];
    }
}

// ---------------------------------------------------------------------------
// Kernel 4: BN apply + ReLU
// ---------------------------------------------------------------------------
__global__ __launch_bounds__(256) void bn_apply(
    const float* __restrict__ outb, const float* __restrict__ stats,
    const float* __restrict__ gamma, const float* __restrict__ beta,
    float* __restrict__ y)
{
    int idx = blockIdx.x * 256 + threadIdx.x;
    size_t i0 = (size_t)idx * 4;
    int o = (int)((i0 / HW_) % CHO_);
    float4 v = *reinterpret_cast<const float4*>(outb + i0);
    const float invN = 1.f / (float)NRED_;
    float mu  = stats[o] * invN;
    float var = stats[CHO_ + o] * invN - mu * mu;
    float inv = rsqrtf(var + BN_EPS_);
    float sc = gamma[o] * inv;
    float sh = beta[o] - mu * sc;
    float4 r;
    r.x = fmaxf(v.x * sc + sh, 0.f);
    r.y = fmaxf(v.y * sc + sh, 0.f);
    r.z = fmaxf(v.z * sc + sh, 0.f);
    r.w = fmaxf(v.w * sc + sh, 0.f);
    *reinterpret_cast<float4*>(y + i0) = r;
}

// ---------------------------------------------------------------------------
extern "C" void kernel_launch(void* const* d_in, const int* in_sizes, int n_in,
                              void* d_out, int out_size, void* d_ws, size_t ws_size,
                              hipStream_t stream)
{
    const float* x   = (const float*)d_in[0];
    const float* wof = (const float*)d_in[1];
    const float* bof = (const float*)d_in[2];
    const float* wcv = (const float*)d_in[3];
    const float* bcv = (const float*)d_in[4];
    const float* gam = (const float*)d_in[5];
    const float* bet = (const float*)d_in[6];
    float* y = (float*)d_out;

    char* ws = (char*)d_ws;
    float*          om    = (float*)ws;                                   // 3.98 MB
    float*          outb  = (float*)(ws + (size_t)4 * 1024 * 1024);       // 36 MB
    float*          stats = (float*)(ws + (size_t)40 * 1024 * 1024);      // 2 KB
    unsigned short* wbf   = (unsigned short*)(ws + (size_t)40 * 1024 * 1024 + 8192);
    unsigned short* wob   = (unsigned short*)(ws + (size_t)40 * 1024 * 1024 + 8192 + 1179648);
    unsigned short* colsb = (unsigned short*)(ws + (size_t)48 * 1024 * 1024);
    const size_t NEED = (size_t)48 * 1024 * 1024 + (size_t)BN_ * HW_ * CK_ * 2; // ~218 MB

    w2b<<<(CHO_ * CK_) / 256, 256, 0, stream>>>(wcv, wbf);
    w2b<<<(27 * CK_) / 256, 256, 0, stream>>>(wof, wob);
    offset_mfma<<<BN_ * (HW_ / TPX_), 256, 0, stream>>>(x, wob, bof, om);

    if (ws_size >= NEED) {
        gather_cols<<<BN_ * (HW_ / 64) * 9, 256, 0, stream>>>(x, om, colsb);
        gemm_cols<<<BN_ * (HW_ / TPX_), 256, 0, stream>>>(colsb, wbf, bcv, outb);
    } else {
        deform_fused<<<BN_ * (HW_ / TPX_), 256, 0, stream>>>(x, om, wbf, bcv, outb);
    }

    bn_stats<<<CHO_, 256, 0, stream>>>(outb, stats);
    bn_apply<<<(BN_ * CHO_ * HW_) / (4 * 256), 256, 0, stream>>>(outb, stats, gam, bet, y);
}

// Round 7
// 778.834 us; speedup vs baseline: 1.1845x; 1.1845x over previous
//
#include <hip/hip_runtime.h>
#include <math.h>

// Problem constants (DeformConv_68109591380935) — ALL TENSORS FLOAT32
#define BN_    4
#define CHI_   256
#define CHO_   256
#define HH_    96
#define WW_    96
#define HW_    (HH_*WW_)        // 9216
#define KK_    9
#define CK_    (CHI_*KK_)       // 2304
#define NRED_  (BN_*HW_)        // 36864 samples per BN channel
#define BN_EPS_ 1e-5f

#define TPX_   64
#define KC_    64               // K-chunk staged in LDS (cols only)
#define PITCH_ 72               // bf16 pitch (64 + 8 pad; 144B rows, 16B aligned)

// offset_mfma tiling
#define OKC_    96
#define OPITCH_ 104

typedef short short8 __attribute__((ext_vector_type(8)));
typedef float f32x4  __attribute__((ext_vector_type(4)));

__device__ __forceinline__ unsigned short f2bf(float v) {
    union { float f; unsigned u; } c; c.f = v;
    unsigned lsb = (c.u >> 16) & 1u;
    c.u += 0x7fffu + lsb;
    return (unsigned short)(c.u >> 16);
}

// bilinear gather of one col element, meta arrays indexed [k*64 + i]
__device__ __forceinline__ float gather_one(
    const float* __restrict__ xb, const float* s_py, const float* s_px,
    const float* s_mask, int jg, int i)
{
    int c = (jg * 7282) >> 16;            // jg/9 (exact for jg<2304)
    int k = jg - 9 * c;
    float py = s_py[k * 64 + i], px = s_px[k * 64 + i];
    float y0f = floorf(py), x0f = floorf(px);
    float ly = py - y0f, lx = px - x0f;
    int y0 = (int)y0f, x0 = (int)x0f;
    float vy0 = ((unsigned)y0       < HH_) ? 1.f : 0.f;
    float vy1 = ((unsigned)(y0 + 1) < HH_) ? 1.f : 0.f;
    float vx0 = ((unsigned)x0       < WW_) ? 1.f : 0.f;
    float vx1 = ((unsigned)(x0 + 1) < WW_) ? 1.f : 0.f;
    int yc0 = min(max(y0, 0), HH_ - 1), yc1 = min(max(y0 + 1, 0), HH_ - 1);
    int xc0 = min(max(x0, 0), WW_ - 1), xc1 = min(max(x0 + 1, 0), WW_ - 1);
    const float* img = xb + (size_t)c * HW_;
    float f00 = img[yc0 * WW_ + xc0];
    float f01 = img[yc0 * WW_ + xc1];
    float f10 = img[yc1 * WW_ + xc0];
    float f11 = img[yc1 * WW_ + xc1];
    float wy0 = 1.f - ly, wx0 = 1.f - lx;
    float v = f00 * (wy0 * wx0 * vy0 * vx0) + f01 * (wy0 * lx * vy0 * vx1)
            + f10 * (ly  * wx0 * vy1 * vx0) + f11 * (ly  * lx * vy1 * vx1);
    return v * s_mask[k * 64 + i];
}

// ---------------------------------------------------------------------------
// Kernel 0: f32 -> bf16 convert
// ---------------------------------------------------------------------------
__global__ __launch_bounds__(256) void w2b(
    const float* __restrict__ w, unsigned short* __restrict__ wb)
{
    int idx = blockIdx.x * 256 + threadIdx.x;
    wb[idx] = f2bf(w[idx]);
}

// ---------------------------------------------------------------------------
// Kernel 1: offset conv as MFMA GEMM (32 oc x 64 px blocks)
// ---------------------------------------------------------------------------
__global__ __launch_bounds__(256) void offset_mfma(
    const float* __restrict__ x, const unsigned short* __restrict__ wob,
    const float* __restrict__ bo, float* __restrict__ om)
{
    __shared__ __align__(16) unsigned short s_w[32 * OPITCH_];
    __shared__ __align__(16) unsigned short s_cols[TPX_ * OPITCH_];

    const int t = threadIdx.x;
    const int pixtile = blockIdx.x % (HW_ / TPX_);
    const int b       = blockIdx.x / (HW_ / TPX_);
    const int p0 = pixtile * TPX_;

    const int lane = t & 63, wave = t >> 6;
    const int quad = lane >> 4, l15 = lane & 15;

    const int i   = t & 63;
    const int jlb = (t >> 6) * 24;
    const int p   = p0 + i;
    const int h   = p / WW_, w = p % WW_;
    const float* xb = x + (size_t)b * CHI_ * HW_;

    f32x4 acc[2];
    acc[0] = (f32x4){0.f,0.f,0.f,0.f};
    acc[1] = (f32x4){0.f,0.f,0.f,0.f};

    for (int kc = 0; kc < CK_ / OKC_; kc++) {
        const int j0 = kc * OKC_;
        if (kc) __syncthreads();
#pragma unroll
        for (int n = 0; n < 3; n++) {
            int e = t + n * 256;
            int ocl = e / 24, kq = e % 24;
            uint2 v = make_uint2(0u, 0u);
            if (ocl < 27)
                v = *reinterpret_cast<const uint2*>(wob + (size_t)ocl * CK_ + j0 + kq * 4);
            *reinterpret_cast<uint2*>(&s_w[ocl * OPITCH_ + kq * 4]) = v;
        }
        union { unsigned short s[24]; uint4 q[3]; } pk;
#pragma unroll
        for (int m = 0; m < 24; m++) {
            int jg = j0 + jlb + m;
            int c  = (jg * 7282) >> 16;
            int k  = jg - 9 * c;
            int yy = h + k / 3 - 1, xx = w + k % 3 - 1;
            bool ok = ((unsigned)yy < HH_) & ((unsigned)xx < WW_);
            float v = ok ? xb[(size_t)c * HW_ + yy * WW_ + xx] : 0.f;
            pk.s[m] = f2bf(v);
        }
        {
            uint4* dst = reinterpret_cast<uint4*>(&s_cols[i * OPITCH_ + jlb]);
            dst[0] = pk.q[0]; dst[1] = pk.q[1]; dst[2] = pk.q[2];
        }
        __syncthreads();
#pragma unroll
        for (int ks = 0; ks < OKC_ / 32; ks++) {
            short8 a0 = *reinterpret_cast<const short8*>(
                &s_w[(l15) * OPITCH_ + ks * 32 + quad * 8]);
            short8 a1 = *reinterpret_cast<const short8*>(
                &s_w[(16 + l15) * OPITCH_ + ks * 32 + quad * 8]);
            short8 b0 = *reinterpret_cast<const short8*>(
                &s_cols[(wave * 16 + l15) * OPITCH_ + ks * 32 + quad * 8]);
            acc[0] = __builtin_amdgcn_mfma_f32_16x16x32_bf16(a0, b0, acc[0], 0, 0, 0);
            acc[1] = __builtin_amdgcn_mfma_f32_16x16x32_bf16(a1, b0, acc[1], 0, 0, 0);
        }
    }
#pragma unroll
    for (int mt = 0; mt < 2; mt++) {
#pragma unroll
        for (int r = 0; r < 4; r++) {
            int oc = mt * 16 + quad * 4 + r;
            if (oc < 27) {
                int pix = p0 + wave * 16 + l15;
                om[((size_t)b * 27 + oc) * HW_ + pix] = acc[mt][r] + bo[oc];
            }
        }
    }
}

// ---------------------------------------------------------------------------
// Kernel 2: fused deformable gather + bf16 MFMA GEMM, NO W staging in LDS.
//   Block: 256 oc x 64 px; 4 waves, each 64 oc x 64 px (4x4 MFMA tiles).
//   A-fragments load directly from global (W is 1.18 MB, L2-resident;
//   per wave-instr: 16 rows x 32 contiguous k = clean 64B segments).
//   LDS = cols (9 KB) + meta (7 KB) -> 4 blocks/CU at VGPR<=128.
// ---------------------------------------------------------------------------
__global__ __launch_bounds__(256, 4) void deform_fused(
    const float* __restrict__ x, const float* __restrict__ om,
    const unsigned short* __restrict__ wb, const float* __restrict__ bconv,
    float* __restrict__ outb)
{
    __shared__ __align__(16) unsigned short s_cols[TPX_ * PITCH_]; // 9216 B
    __shared__ float s_py[KK_ * TPX_], s_px[KK_ * TPX_], s_mask[KK_ * TPX_]; // 6912 B

    const int t = threadIdx.x;
    const int pixtile = blockIdx.x % (HW_ / TPX_);
    const int b       = blockIdx.x / (HW_ / TPX_);
    const int p0 = pixtile * TPX_;

    for (int e = t; e < KK_ * TPX_; e += 256) {
        int k = e / TPX_, i = e % TPX_;
        int p = p0 + i;
        int h = p / WW_, w = p % WW_;
        const float* omb = om + ((size_t)b * 27) * HW_ + p;
        float dy = omb[(2 * k) * HW_];
        float dx = omb[(2 * k + 1) * HW_];
        float m  = omb[(18 + k) * HW_];
        s_py[e]   = dy + (float)(h + k / 3 - 1);
        s_px[e]   = dx + (float)(w + (k % 3) - 1);
        s_mask[e] = 1.f / (1.f + __expf(-m));
    }

    const int lane = t & 63, wave = t >> 6;
    const int quad = lane >> 4, l15 = lane & 15;
    const int ib   = t & 63;           // pixel (staging role)
    const int jlb  = (t >> 6) << 4;    // 0,16,32,48

    f32x4 acc[4][4];
#pragma unroll
    for (int m = 0; m < 4; m++)
#pragma unroll
        for (int n = 0; n < 4; n++)
            acc[m][n] = (f32x4){0.f, 0.f, 0.f, 0.f};

    const float* xb = x + (size_t)b * CHI_ * HW_;
    const unsigned short* wbase = wb + (size_t)(wave * 64 + l15) * CK_;

    __syncthreads();   // meta visible

    for (int kc = 0; kc < CK_ / KC_; kc++) {       // 36 chunks
        const int j0 = kc * KC_;
        if (kc) __syncthreads();
        // ---- stage cols: 64 k x 64 px bilinear gather, 16/thread, 2x b128
        union { unsigned short s[16]; uint4 q[2]; } pk;
#pragma unroll
        for (int m = 0; m < 16; m++)
            pk.s[m] = f2bf(gather_one(xb, s_py, s_px, s_mask, j0 + jlb + m, ib));
        {
            uint4* dst = reinterpret_cast<uint4*>(&s_cols[ib * PITCH_ + jlb]);
            dst[0] = pk.q[0]; dst[1] = pk.q[1];
        }
        __syncthreads();
        // ---- MFMA: 2 K-steps of 32; A from global (L2), B from LDS ----
#pragma unroll
        for (int ks = 0; ks < KC_ / 32; ks++) {
            const int k0 = j0 + ks * 32 + quad * 8;
            short8 afr[4], bfr[4];
#pragma unroll
            for (int m = 0; m < 4; m++)
                afr[m] = *reinterpret_cast<const short8*>(
                    wbase + (size_t)m * 16 * CK_ + k0);
#pragma unroll
            for (int n = 0; n < 4; n++)
                bfr[n] = *reinterpret_cast<const short8*>(
                    &s_cols[(n * 16 + l15) * PITCH_ + ks * 32 + quad * 8]);
#pragma unroll
            for (int m = 0; m < 4; m++)
#pragma unroll
                for (int n = 0; n < 4; n++)
                    acc[m][n] = __builtin_amdgcn_mfma_f32_16x16x32_bf16(
                        afr[m], bfr[n], acc[m][n], 0, 0, 0);
        }
    }

    // ---- epilogue: C/D layout col=lane&15 (pixel), row=quad*4+r (oc) ----
#pragma unroll
    for (int m = 0; m < 4; m++)
#pragma unroll
        for (int n = 0; n < 4; n++)
#pragma unroll
            for (int r = 0; r < 4; r++) {
                int oc  = wave * 64 + m * 16 + quad * 4 + r;
                int pix = p0 + n * 16 + l15;
                outb[((size_t)b * CHO_ + oc) * HW_ + pix] = acc[m][n][r] + bconv[oc];
            }
}

// ---------------------------------------------------------------------------
// Kernel 3: BN statistics (sum, sumsq) per channel, deterministic two-pass
// ---------------------------------------------------------------------------
__global__ __launch_bounds__(256) void bn_stats(
    const float* __restrict__ outb, float* __restrict__ stats)
{
    int o = blockIdx.x, t = threadIdx.x;
    float s = 0.f, s2 = 0.f;
    for (int b = 0; b < BN_; b++) {
        const float* base = outb + ((size_t)b * CHO_ + o) * HW_;
        for (int p = t; p < HW_; p += 256) {
            float v = base[p];
            s += v; s2 += v * v;
        }
    }
#pragma unroll
    for (int off = 32; off > 0; off >>= 1) {
        s  += __shfl_down(s,  off, 64);
        s2 += __shfl_down(s2, off, 64);
    }
    __shared__ float rs[4], rs2[4];
    int lane = t & 63, wv = t >> 6;
    if (lane == 0) { rs[wv] = s; rs2[wv] = s2; }
    __syncthreads();
    if (t == 0) {
        stats[o]        = rs[0] + rs[1] + rs[2] + rs[3];
        stats[CHO_ + o] = rs2[0] + rs2[1] + rs2[2] + rs2[3];
    }
}

// ---------------------------------------------------------------------------
// Kernel 4: BN apply + ReLU
// ---------------------------------------------------------------------------
__global__ __launch_bounds__(256) void bn_apply(
    const float* __restrict__ outb, const float* __restrict__ stats,
    const float* __restrict__ gamma, const float* __restrict__ beta,
    float* __restrict__ y)
{
    int idx = blockIdx.x * 256 + threadIdx.x;
    size_t i0 = (size_t)idx * 4;
    int o = (int)((i0 / HW_) % CHO_);
    float4 v = *reinterpret_cast<const float4*>(outb + i0);
    const float invN = 1.f / (float)NRED_;
    float mu  = stats[o] * invN;
    float var = stats[CHO_ + o] * invN - mu * mu;
    float inv = rsqrtf(var + BN_EPS_);
    float sc = gamma[o] * inv;
    float sh = beta[o] - mu * sc;
    float4 r;
    r.x = fmaxf(v.x * sc + sh, 0.f);
    r.y = fmaxf(v.y * sc + sh, 0.f);
    r.z = fmaxf(v.z * sc + sh, 0.f);
    r.w = fmaxf(v.w * sc + sh, 0.f);
    *reinterpret_cast<float4*>(y + i0) = r;
}

// ---------------------------------------------------------------------------
extern "C" void kernel_launch(void* const* d_in, const int* in_sizes, int n_in,
                              void* d_out, int out_size, void* d_ws, size_t ws_size,
                              hipStream_t stream)
{
    const float* x   = (const float*)d_in[0];
    const float* wof = (const float*)d_in[1];
    const float* bof = (const float*)d_in[2];
    const float* wcv = (const float*)d_in[3];
    const float* bcv = (const float*)d_in[4];
    const float* gam = (const float*)d_in[5];
    const float* bet = (const float*)d_in[6];
    float* y = (float*)d_out;

    char* ws = (char*)d_ws;
    float*          om    = (float*)ws;                                   // 3.98 MB
    float*          outb  = (float*)(ws + (size_t)4 * 1024 * 1024);       // 36 MB
    float*          stats = (float*)(ws + (size_t)40 * 1024 * 1024);      // 2 KB
    unsigned short* wbf   = (unsigned short*)(ws + (size_t)40 * 1024 * 1024 + 8192);
    unsigned short* wob   = (unsigned short*)(ws + (size_t)40 * 1024 * 1024 + 8192 + 1179648);

    w2b<<<(CHO_ * CK_) / 256, 256, 0, stream>>>(wcv, wbf);
    w2b<<<(27 * CK_) / 256, 256, 0, stream>>>(wof, wob);
    offset_mfma<<<BN_ * (HW_ / TPX_), 256, 0, stream>>>(x, wob, bof, om);
    deform_fused<<<BN_ * (HW_ / TPX_), 256, 0, stream>>>(x, om, wbf, bcv, outb);
    bn_stats<<<CHO_, 256, 0, stream>>>(outb, stats);
    bn_apply<<<(BN_ * CHO_ * HW_) / (4 * 256), 256, 0, stream>>>(outb, stats, gam, bet, y);
}

// Round 8
// 666.118 us; speedup vs baseline: 1.3849x; 1.1692x over previous
//
#include <hip/hip_runtime.h>
#include <math.h>

// Problem constants (DeformConv_68109591380935) — ALL TENSORS FLOAT32
#define BN_    4
#define CHI_   256
#define CHO_   256
#define HH_    96
#define WW_    96
#define HW_    (HH_*WW_)        // 9216
#define KK_    9
#define CK_    (CHI_*KK_)       // 2304
#define NRED_  (BN_*HW_)        // 36864 samples per BN channel
#define BN_EPS_ 1e-5f

// deform_part tiling: 256 oc x 32 px x K-quarter per block
#define SPX_   32               // pixels per block
#define KC_    64               // K-chunk staged in LDS
#define PITCH_ 72               // bf16 pitch (64 + 8 pad)
#define KSPL_  4                // split-K ways
#define KQ_    (CK_/KSPL_)      // 576 j per slice
#define NPART_ ((size_t)BN_*CHO_*HW_)   // elements per partial buffer

// offset_mfma tiling
#define TPX_    64
#define OKC_    96
#define OPITCH_ 104

typedef short short8 __attribute__((ext_vector_type(8)));
typedef float f32x4  __attribute__((ext_vector_type(4)));

__device__ __forceinline__ unsigned short f2bf(float v) {
    union { float f; unsigned u; } c; c.f = v;
    unsigned lsb = (c.u >> 16) & 1u;
    c.u += 0x7fffu + lsb;
    return (unsigned short)(c.u >> 16);
}

// bilinear gather of one col element; meta arrays indexed [k*STRIDE + i]
template <int STRIDE>
__device__ __forceinline__ float gather_one(
    const float* __restrict__ xb, const float* s_py, const float* s_px,
    const float* s_mask, int jg, int i)
{
    int c = (jg * 7282) >> 16;            // jg/9 (exact for jg<2304)
    int k = jg - 9 * c;
    float py = s_py[k * STRIDE + i], px = s_px[k * STRIDE + i];
    float y0f = floorf(py), x0f = floorf(px);
    float ly = py - y0f, lx = px - x0f;
    int y0 = (int)y0f, x0 = (int)x0f;
    float vy0 = ((unsigned)y0       < HH_) ? 1.f : 0.f;
    float vy1 = ((unsigned)(y0 + 1) < HH_) ? 1.f : 0.f;
    float vx0 = ((unsigned)x0       < WW_) ? 1.f : 0.f;
    float vx1 = ((unsigned)(x0 + 1) < WW_) ? 1.f : 0.f;
    int yc0 = min(max(y0, 0), HH_ - 1), yc1 = min(max(y0 + 1, 0), HH_ - 1);
    int xc0 = min(max(x0, 0), WW_ - 1), xc1 = min(max(x0 + 1, 0), WW_ - 1);
    const float* img = xb + (size_t)c * HW_;
    float f00 = img[yc0 * WW_ + xc0];
    float f01 = img[yc0 * WW_ + xc1];
    float f10 = img[yc1 * WW_ + xc0];
    float f11 = img[yc1 * WW_ + xc1];
    float wy0 = 1.f - ly, wx0 = 1.f - lx;
    float v = f00 * (wy0 * wx0 * vy0 * vx0) + f01 * (wy0 * lx * vy0 * vx1)
            + f10 * (ly  * wx0 * vy1 * vx0) + f11 * (ly  * lx * vy1 * vx1);
    return v * s_mask[k * STRIDE + i];
}

// ---------------------------------------------------------------------------
// Kernel 0: f32 -> bf16 convert
// ---------------------------------------------------------------------------
__global__ __launch_bounds__(256) void w2b(
    const float* __restrict__ w, unsigned short* __restrict__ wb)
{
    int idx = blockIdx.x * 256 + threadIdx.x;
    wb[idx] = f2bf(w[idx]);
}

// ---------------------------------------------------------------------------
// Kernel 1: offset conv as MFMA GEMM (32 oc x 64 px blocks) — unchanged
// ---------------------------------------------------------------------------
__global__ __launch_bounds__(256) void offset_mfma(
    const float* __restrict__ x, const unsigned short* __restrict__ wob,
    const float* __restrict__ bo, float* __restrict__ om)
{
    __shared__ __align__(16) unsigned short s_w[32 * OPITCH_];
    __shared__ __align__(16) unsigned short s_cols[TPX_ * OPITCH_];

    const int t = threadIdx.x;
    const int pixtile = blockIdx.x % (HW_ / TPX_);
    const int b       = blockIdx.x / (HW_ / TPX_);
    const int p0 = pixtile * TPX_;

    const int lane = t & 63, wave = t >> 6;
    const int quad = lane >> 4, l15 = lane & 15;

    const int i   = t & 63;
    const int jlb = (t >> 6) * 24;
    const int p   = p0 + i;
    const int h   = p / WW_, w = p % WW_;
    const float* xb = x + (size_t)b * CHI_ * HW_;

    f32x4 acc[2];
    acc[0] = (f32x4){0.f,0.f,0.f,0.f};
    acc[1] = (f32x4){0.f,0.f,0.f,0.f};

    for (int kc = 0; kc < CK_ / OKC_; kc++) {
        const int j0 = kc * OKC_;
        if (kc) __syncthreads();
#pragma unroll
        for (int n = 0; n < 3; n++) {
            int e = t + n * 256;
            int ocl = e / 24, kq = e % 24;
            uint2 v = make_uint2(0u, 0u);
            if (ocl < 27)
                v = *reinterpret_cast<const uint2*>(wob + (size_t)ocl * CK_ + j0 + kq * 4);
            *reinterpret_cast<uint2*>(&s_w[ocl * OPITCH_ + kq * 4]) = v;
        }
        union { unsigned short s[24]; uint4 q[3]; } pk;
#pragma unroll
        for (int m = 0; m < 24; m++) {
            int jg = j0 + jlb + m;
            int c  = (jg * 7282) >> 16;
            int k  = jg - 9 * c;
            int yy = h + k / 3 - 1, xx = w + k % 3 - 1;
            bool ok = ((unsigned)yy < HH_) & ((unsigned)xx < WW_);
            float v = ok ? xb[(size_t)c * HW_ + yy * WW_ + xx] : 0.f;
            pk.s[m] = f2bf(v);
        }
        {
            uint4* dst = reinterpret_cast<uint4*>(&s_cols[i * OPITCH_ + jlb]);
            dst[0] = pk.q[0]; dst[1] = pk.q[1]; dst[2] = pk.q[2];
        }
        __syncthreads();
#pragma unroll
        for (int ks = 0; ks < OKC_ / 32; ks++) {
            short8 a0 = *reinterpret_cast<const short8*>(
                &s_w[(l15) * OPITCH_ + ks * 32 + quad * 8]);
            short8 a1 = *reinterpret_cast<const short8*>(
                &s_w[(16 + l15) * OPITCH_ + ks * 32 + quad * 8]);
            short8 b0 = *reinterpret_cast<const short8*>(
                &s_cols[(wave * 16 + l15) * OPITCH_ + ks * 32 + quad * 8]);
            acc[0] = __builtin_amdgcn_mfma_f32_16x16x32_bf16(a0, b0, acc[0], 0, 0, 0);
            acc[1] = __builtin_amdgcn_mfma_f32_16x16x32_bf16(a1, b0, acc[1], 0, 0, 0);
        }
    }
#pragma unroll
    for (int mt = 0; mt < 2; mt++) {
#pragma unroll
        for (int r = 0; r < 4; r++) {
            int oc = mt * 16 + quad * 4 + r;
            if (oc < 27) {
                int pix = p0 + wave * 16 + l15;
                om[((size_t)b * 27 + oc) * HW_ + pix] = acc[mt][r] + bo[oc];
            }
        }
    }
}

// ---------------------------------------------------------------------------
// Kernel 2: split-K fused gather + MFMA partial GEMM.
//   Block = (b, px-tile of 32, K-quarter of 576). 256 oc per block.
//   4 waves, wave = 64 oc x 32 px (4x2 MFMA tiles, 32 acc AGPRs).
//   Every col element gathered exactly once across the grid.
//   A-fragments direct from global (W bf16, L2-resident). No forced bounds.
// ---------------------------------------------------------------------------
__global__ __launch_bounds__(256) void deform_part(
    const float* __restrict__ x, const float* __restrict__ om,
    const unsigned short* __restrict__ wb, const float* __restrict__ bconv,
    float* __restrict__ partb)
{
    __shared__ __align__(16) unsigned short s_cols[SPX_ * PITCH_]; // 4608 B
    __shared__ float s_py[KK_ * SPX_], s_px[KK_ * SPX_], s_mask[KK_ * SPX_]; // 3456 B

    const int t = threadIdx.x;
    const int kslice  = blockIdx.x & (KSPL_ - 1);
    const int pixtile = (blockIdx.x >> 2) % (HW_ / SPX_);  // 288
    const int b       = blockIdx.x / (KSPL_ * (HW_ / SPX_));
    const int p0 = pixtile * SPX_;

    // meta: 9 taps x 32 px
    for (int e = t; e < KK_ * SPX_; e += 256) {
        int k = e / SPX_, i = e % SPX_;
        int p = p0 + i;
        int h = p / WW_, w = p % WW_;
        const float* omb = om + ((size_t)b * 27) * HW_ + p;
        float dy = omb[(2 * k) * HW_];
        float dx = omb[(2 * k + 1) * HW_];
        float m  = omb[(18 + k) * HW_];
        s_py[e]   = dy + (float)(h + k / 3 - 1);
        s_px[e]   = dx + (float)(w + (k % 3) - 1);
        s_mask[e] = 1.f / (1.f + __expf(-m));
    }

    const int lane = t & 63, wave = t >> 6;
    const int quad = lane >> 4, l15 = lane & 15;
    const int ip = t & 31;             // pixel (staging role)
    const int jb = (t >> 5) * 8;       // j-subrange (8 of 64)

    f32x4 acc[4][2];
#pragma unroll
    for (int m = 0; m < 4; m++)
#pragma unroll
        for (int n = 0; n < 2; n++)
            acc[m][n] = (f32x4){0.f, 0.f, 0.f, 0.f};

    const float* xb = x + (size_t)b * CHI_ * HW_;
    const unsigned short* wbase = wb + (size_t)(wave * 64 + l15) * CK_;
    const int jk0 = kslice * KQ_;

    __syncthreads();   // meta visible

    for (int kc = 0; kc < KQ_ / KC_; kc++) {       // 9 chunks
        const int j0 = jk0 + kc * KC_;
        if (kc) __syncthreads();
        // ---- stage cols: 64 k x 32 px gather, 8 el/thread, 1x b128 write
        union { unsigned short s[8]; uint4 q; } pk;
#pragma unroll
        for (int m = 0; m < 8; m++)
            pk.s[m] = f2bf(gather_one<SPX_>(xb, s_py, s_px, s_mask, j0 + jb + m, ip));
        *reinterpret_cast<uint4*>(&s_cols[ip * PITCH_ + jb]) = pk.q;
        __syncthreads();
        // ---- MFMA: 2 K-steps of 32; A from global (L2), B from LDS ----
#pragma unroll
        for (int ks = 0; ks < KC_ / 32; ks++) {
            const int k0 = j0 + ks * 32 + quad * 8;
            short8 afr[4], bfr[2];
#pragma unroll
            for (int m = 0; m < 4; m++)
                afr[m] = *reinterpret_cast<const short8*>(
                    wbase + (size_t)m * 16 * CK_ + k0);
#pragma unroll
            for (int n = 0; n < 2; n++)
                bfr[n] = *reinterpret_cast<const short8*>(
                    &s_cols[(n * 16 + l15) * PITCH_ + ks * 32 + quad * 8]);
#pragma unroll
            for (int m = 0; m < 4; m++)
#pragma unroll
                for (int n = 0; n < 2; n++)
                    acc[m][n] = __builtin_amdgcn_mfma_f32_16x16x32_bf16(
                        afr[m], bfr[n], acc[m][n], 0, 0, 0);
        }
    }

    // ---- epilogue: partial store; kslice 0 carries the bias ----
    float* pb = partb + (size_t)kslice * NPART_;
    const bool addb = (kslice == 0);
#pragma unroll
    for (int m = 0; m < 4; m++)
#pragma unroll
        for (int n = 0; n < 2; n++)
#pragma unroll
            for (int r = 0; r < 4; r++) {
                int oc  = wave * 64 + m * 16 + quad * 4 + r;
                int pix = p0 + n * 16 + l15;
                float v = acc[m][n][r] + (addb ? bconv[oc] : 0.f);
                pb[((size_t)b * CHO_ + oc) * HW_ + pix] = v;
            }
}

// ---------------------------------------------------------------------------
// Kernel 3: BN statistics over the 4 summed partials (deterministic order)
// ---------------------------------------------------------------------------
__global__ __launch_bounds__(256) void bn_stats(
    const float* __restrict__ partb, float* __restrict__ stats)
{
    int o = blockIdx.x, t = threadIdx.x;
    float s = 0.f, s2 = 0.f;
    for (int b = 0; b < BN_; b++) {
        size_t base = ((size_t)b * CHO_ + o) * HW_;
        for (int p = t; p < HW_; p += 256) {
            float v = partb[base + p] + partb[NPART_ + base + p]
                    + partb[2 * NPART_ + base + p] + partb[3 * NPART_ + base + p];
            s += v; s2 += v * v;
        }
    }
#pragma unroll
    for (int off = 32; off > 0; off >>= 1) {
        s  += __shfl_down(s,  off, 64);
        s2 += __shfl_down(s2, off, 64);
    }
    __shared__ float rs[4], rs2[4];
    int lane = t & 63, wv = t >> 6;
    if (lane == 0) { rs[wv] = s; rs2[wv] = s2; }
    __syncthreads();
    if (t == 0) {
        stats[o]        = rs[0] + rs[1] + rs[2] + rs[3];
        stats[CHO_ + o] = rs2[0] + rs2[1] + rs2[2] + rs2[3];
    }
}

// ---------------------------------------------------------------------------
// Kernel 4: BN apply + ReLU from summed partials
// ---------------------------------------------------------------------------
__global__ __launch_bounds__(256) void bn_apply(
    const float* __restrict__ partb, const float* __restrict__ stats,
    const float* __restrict__ gamma, const float* __restrict__ beta,
    float* __restrict__ y)
{
    int idx = blockIdx.x * 256 + threadIdx.x;
    size_t i0 = (size_t)idx * 4;
    int o = (int)((i0 / HW_) % CHO_);
    float4 v0 = *reinterpret_cast<const float4*>(partb + i0);
    float4 v1 = *reinterpret_cast<const float4*>(partb + NPART_ + i0);
    float4 v2 = *reinterpret_cast<const float4*>(partb + 2 * NPART_ + i0);
    float4 v3 = *reinterpret_cast<const float4*>(partb + 3 * NPART_ + i0);
    float4 v;
    v.x = v0.x + v1.x + v2.x + v3.x;
    v.y = v0.y + v1.y + v2.y + v3.y;
    v.z = v0.z + v1.z + v2.z + v3.z;
    v.w = v0.w + v1.w + v2.w + v3.w;
    const float invN = 1.f / (float)NRED_;
    float mu  = stats[o] * invN;
    float var = stats[CHO_ + o] * invN - mu * mu;
    float inv = rsqrtf(var + BN_EPS_);
    float sc = gamma[o] * inv;
    float sh = beta[o] - mu * sc;
    float4 r;
    r.x = fmaxf(v.x * sc + sh, 0.f);
    r.y = fmaxf(v.y * sc + sh, 0.f);
    r.z = fmaxf(v.z * sc + sh, 0.f);
    r.w = fmaxf(v.w * sc + sh, 0.f);
    *reinterpret_cast<float4*>(y + i0) = r;
}

// ---------------------------------------------------------------------------
extern "C" void kernel_launch(void* const* d_in, const int* in_sizes, int n_in,
                              void* d_out, int out_size, void* d_ws, size_t ws_size,
                              hipStream_t stream)
{
    const float* x   = (const float*)d_in[0];
    const float* wof = (const float*)d_in[1];
    const float* bof = (const float*)d_in[2];
    const float* wcv = (const float*)d_in[3];
    const float* bcv = (const float*)d_in[4];
    const float* gam = (const float*)d_in[5];
    const float* bet = (const float*)d_in[6];
    float* y = (float*)d_out;

    char* ws = (char*)d_ws;
    float*          om    = (float*)ws;                                   // 3.98 MB
    float*          stats = (float*)(ws + (size_t)40 * 1024 * 1024);      // 2 KB
    unsigned short* wbf   = (unsigned short*)(ws + (size_t)40 * 1024 * 1024 + 8192);
    unsigned short* wob   = (unsigned short*)(ws + (size_t)40 * 1024 * 1024 + 8192 + 1179648);
    float*          partb = (float*)(ws + (size_t)48 * 1024 * 1024);      // 4 x 36 MB (ws >= 218 MB confirmed R6)

    w2b<<<(CHO_ * CK_) / 256, 256, 0, stream>>>(wcv, wbf);
    w2b<<<(27 * CK_) / 256, 256, 0, stream>>>(wof, wob);
    offset_mfma<<<BN_ * (HW_ / TPX_), 256, 0, stream>>>(x, wob, bof, om);
    deform_part<<<BN_ * (HW_ / SPX_) * KSPL_, 256, 0, stream>>>(x, om, wbf, bcv, partb);
    bn_stats<<<CHO_, 256, 0, stream>>>(partb, stats);
    bn_apply<<<(BN_ * CHO_ * HW_) / (4 * 256), 256, 0, stream>>>(partb, stats, gam, bet, y);
}

// Round 10
// 590.289 us; speedup vs baseline: 1.5628x; 1.1285x over previous
//
#include <hip/hip_runtime.h>
#include <math.h>

// Problem constants (DeformConv_68109591380935) — ALL TENSORS FLOAT32
#define BN_    4
#define CHI_   256
#define CHO_   256
#define HH_    96
#define WW_    96
#define HW_    (HH_*WW_)        // 9216
#define KK_    9
#define CK_    (CHI_*KK_)       // 2304
#define NRED_  (BN_*HW_)        // 36864 samples per BN channel
#define BN_EPS_ 1e-5f

// deform_part tiling: 256 oc x 32 px x K-quarter (576 j) per block.
// Channel-major j = c*9+k; one slice = 64 channels x 9 taps. Whole slice
// staged in LDS once -> ONE barrier pair per block.
#define SPX_    32              // pixels per block
#define KSPL_   4               // split-K ways
#define KQ_     (CK_/KSPL_)     // 576 j per slice
#define SPITCH_ 584             // bf16 row pitch (576 + 8; 1168 B = 73*16, 16B-aligned)
#define NPART_  ((size_t)BN_*CHO_*HW_)  // elements per partial buffer

// offset_mfma tiling
#define TPX_    64
#define OKC_    96
#define OPITCH_ 104

typedef short short8 __attribute__((ext_vector_type(8)));
typedef float f32x4  __attribute__((ext_vector_type(4)));

__device__ __forceinline__ unsigned short f2bf(float v) {
    union { float f; unsigned u; } c; c.f = v;
    unsigned lsb = (c.u >> 16) & 1u;
    c.u += 0x7fffu + lsb;
    return (unsigned short)(c.u >> 16);
}

// per-(tap,pixel) gather meta: 4 clamped offsets + 4 weights (valid folded).
// NOTE: mask multiplied at the end (matches R8's rounding exactly).
struct TapMeta { int o00, o01, o10, o11; float w00, w01, w10, w11; float mk; };

__device__ __forceinline__ TapMeta make_meta(
    const float* s_py, const float* s_px, const float* s_mask, int tap, int ip)
{
    TapMeta m;
    float py = s_py[tap * SPX_ + ip];
    float px = s_px[tap * SPX_ + ip];
    m.mk = s_mask[tap * SPX_ + ip];
    float y0f = floorf(py), x0f = floorf(px);
    float ly = py - y0f, lx = px - x0f;
    int y0 = (int)y0f, x0 = (int)x0f;
    float vy0 = ((unsigned)y0       < HH_) ? 1.f : 0.f;
    float vy1 = ((unsigned)(y0 + 1) < HH_) ? 1.f : 0.f;
    float vx0 = ((unsigned)x0       < WW_) ? 1.f : 0.f;
    float vx1 = ((unsigned)(x0 + 1) < WW_) ? 1.f : 0.f;
    int yc0 = min(max(y0, 0), HH_ - 1), yc1 = min(max(y0 + 1, 0), HH_ - 1);
    int xc0 = min(max(x0, 0), WW_ - 1), xc1 = min(max(x0 + 1, 0), WW_ - 1);
    m.o00 = yc0 * WW_ + xc0; m.o01 = yc0 * WW_ + xc1;
    m.o10 = yc1 * WW_ + xc0; m.o11 = yc1 * WW_ + xc1;
    float wy0 = 1.f - ly, wx0 = 1.f - lx;
    m.w00 = wy0 * wx0 * vy0 * vx0;
    m.w01 = wy0 * lx  * vy0 * vx1;
    m.w10 = ly  * wx0 * vy1 * vx0;
    m.w11 = ly  * lx  * vy1 * vx1;
    return m;
}

// ---------------------------------------------------------------------------
// Kernel 0: plain f32 -> bf16 (both weight tensors, original c*9+k order)
// ---------------------------------------------------------------------------
__global__ __launch_bounds__(256) void w2b(
    const float* __restrict__ w, unsigned short* __restrict__ wb)
{
    int idx = blockIdx.x * 256 + threadIdx.x;
    wb[idx] = f2bf(w[idx]);
}

// ---------------------------------------------------------------------------
// Kernel 1: offset conv as MFMA GEMM (32 oc x 64 px blocks) — unchanged
// ---------------------------------------------------------------------------
__global__ __launch_bounds__(256) void offset_mfma(
    const float* __restrict__ x, const unsigned short* __restrict__ wob,
    const float* __restrict__ bo, float* __restrict__ om)
{
    __shared__ __align__(16) unsigned short s_w[32 * OPITCH_];
    __shared__ __align__(16) unsigned short s_cols[TPX_ * OPITCH_];

    const int t = threadIdx.x;
    const int pixtile = blockIdx.x % (HW_ / TPX_);
    const int b       = blockIdx.x / (HW_ / TPX_);
    const int p0 = pixtile * TPX_;

    const int lane = t & 63, wave = t >> 6;
    const int quad = lane >> 4, l15 = lane & 15;

    const int i   = t & 63;
    const int jlb = (t >> 6) * 24;
    const int p   = p0 + i;
    const int h   = p / WW_, w = p % WW_;
    const float* xb = x + (size_t)b * CHI_ * HW_;

    f32x4 acc[2];
    acc[0] = (f32x4){0.f,0.f,0.f,0.f};
    acc[1] = (f32x4){0.f,0.f,0.f,0.f};

    for (int kc = 0; kc < CK_ / OKC_; kc++) {
        const int j0 = kc * OKC_;
        if (kc) __syncthreads();
#pragma unroll
        for (int n = 0; n < 3; n++) {
            int e = t + n * 256;
            int ocl = e / 24, kq = e % 24;
            uint2 v = make_uint2(0u, 0u);
            if (ocl < 27)
                v = *reinterpret_cast<const uint2*>(wob + (size_t)ocl * CK_ + j0 + kq * 4);
            *reinterpret_cast<uint2*>(&s_w[ocl * OPITCH_ + kq * 4]) = v;
        }
        union { unsigned short s[24]; uint4 q[3]; } pk;
#pragma unroll
        for (int m = 0; m < 24; m++) {
            int jg = j0 + jlb + m;
            int c  = (jg * 7282) >> 16;
            int k  = jg - 9 * c;
            int yy = h + k / 3 - 1, xx = w + k % 3 - 1;
            bool ok = ((unsigned)yy < HH_) & ((unsigned)xx < WW_);
            float v = ok ? xb[(size_t)c * HW_ + yy * WW_ + xx] : 0.f;
            pk.s[m] = f2bf(v);
        }
        {
            uint4* dst = reinterpret_cast<uint4*>(&s_cols[i * OPITCH_ + jlb]);
            dst[0] = pk.q[0]; dst[1] = pk.q[1]; dst[2] = pk.q[2];
        }
        __syncthreads();
#pragma unroll
        for (int ks = 0; ks < OKC_ / 32; ks++) {
            short8 a0 = *reinterpret_cast<const short8*>(
                &s_w[(l15) * OPITCH_ + ks * 32 + quad * 8]);
            short8 a1 = *reinterpret_cast<const short8*>(
                &s_w[(16 + l15) * OPITCH_ + ks * 32 + quad * 8]);
            short8 b0 = *reinterpret_cast<const short8*>(
                &s_cols[(wave * 16 + l15) * OPITCH_ + ks * 32 + quad * 8]);
            acc[0] = __builtin_amdgcn_mfma_f32_16x16x32_bf16(a0, b0, acc[0], 0, 0, 0);
            acc[1] = __builtin_amdgcn_mfma_f32_16x16x32_bf16(a1, b0, acc[1], 0, 0, 0);
        }
    }
#pragma unroll
    for (int mt = 0; mt < 2; mt++) {
#pragma unroll
        for (int r = 0; r < 4; r++) {
            int oc = mt * 16 + quad * 4 + r;
            if (oc < 27) {
                int pix = p0 + wave * 16 + l15;
                om[((size_t)b * 27 + oc) * HW_ + pix] = acc[mt][r] + bo[oc];
            }
        }
    }
}

// ---------------------------------------------------------------------------
// Kernel 2: split-K fused gather + MFMA partial GEMM, ONE barrier pair.
//   Block = (b, px-tile of 32, K-quarter = 64 channels x 9 taps). 256 oc.
//   Stage: thread (ip = pixel, g = channel-octet) loops 9 taps; meta computed
//   once per tap in registers; 288 gather loads pipeline freely.
//   s_cols layout: [pixel][j] channel-major j = c_local*9+tap -> GEMM walks
//   j in EXACTLY R8's order with unpermuted W (bitwise-identical output).
// ---------------------------------------------------------------------------
__global__ __launch_bounds__(256) void deform_part(
    const float* __restrict__ x, const float* __restrict__ om,
    const unsigned short* __restrict__ wb, const float* __restrict__ bconv,
    float* __restrict__ partb)
{
    __shared__ __align__(16) unsigned short s_cols[SPX_ * SPITCH_]; // 37376 B
    __shared__ float s_py[KK_ * SPX_], s_px[KK_ * SPX_], s_mask[KK_ * SPX_]; // 3456 B

    const int t = threadIdx.x;
    const int kslice  = blockIdx.x & (KSPL_ - 1);
    const int pixtile = (blockIdx.x >> 2) % (HW_ / SPX_);  // 288
    const int b       = blockIdx.x / (KSPL_ * (HW_ / SPX_));
    const int p0 = pixtile * SPX_;

    // meta staging: 9 taps x 32 px
    for (int e = t; e < KK_ * SPX_; e += 256) {
        int k = e / SPX_, i = e % SPX_;
        int p = p0 + i;
        int h = p / WW_, w = p % WW_;
        const float* omb = om + ((size_t)b * 27) * HW_ + p;
        float dy = omb[(2 * k) * HW_];
        float dx = omb[(2 * k + 1) * HW_];
        float m  = omb[(18 + k) * HW_];
        s_py[e]   = dy + (float)(h + k / 3 - 1);
        s_px[e]   = dx + (float)(w + (k % 3) - 1);
        s_mask[e] = 1.f / (1.f + __expf(-m));
    }

    const int lane = t & 63, wave = t >> 6;
    const int quad = lane >> 4, l15 = lane & 15;
    const int ip = t & 31;             // pixel (staging role)
    const int g  = t >> 5;             // channel-octet 0..7 within slice

    const float* xb = x + (size_t)b * CHI_ * HW_;

    __syncthreads();   // meta visible

    // ---- stage the whole 576-j slice: 9 taps x 8 channels per thread ----
    {
        unsigned short* srow = &s_cols[ip * SPITCH_];
        const int c0 = kslice * 64 + g * 8;        // absolute channel base
        const float* img0 = xb + (size_t)c0 * HW_;
#pragma unroll 1
        for (int tap = 0; tap < KK_; tap++) {
            TapMeta mt = make_meta(s_py, s_px, s_mask, tap, ip);
#pragma unroll
            for (int cc = 0; cc < 8; cc++) {
                const float* img = img0 + (size_t)cc * HW_;
                float v = mt.w00 * img[mt.o00] + mt.w01 * img[mt.o01]
                        + mt.w10 * img[mt.o10] + mt.w11 * img[mt.o11];
                srow[(g * 8 + cc) * 9 + tap] = f2bf(v * mt.mk);
            }
        }
    }
    __syncthreads();

    // ---- MFMA: 18 K-steps of 32 over the slice; A direct from global/L2 ----
    f32x4 acc[4][2];
#pragma unroll
    for (int m = 0; m < 4; m++)
#pragma unroll
        for (int n = 0; n < 2; n++)
            acc[m][n] = (f32x4){0.f, 0.f, 0.f, 0.f};

    const unsigned short* wbase = wb + (size_t)(wave * 64 + l15) * CK_;
    const int jk0 = kslice * KQ_;

#pragma unroll 1
    for (int ks = 0; ks < KQ_ / 32; ks++) {        // 18
        const int kloc = ks * 32 + quad * 8;
        short8 afr[4], bfr[2];
#pragma unroll
        for (int m = 0; m < 4; m++)
            afr[m] = *reinterpret_cast<const short8*>(
                wbase + (size_t)m * 16 * CK_ + jk0 + kloc);
#pragma unroll
        for (int n = 0; n < 2; n++)
            bfr[n] = *reinterpret_cast<const short8*>(
                &s_cols[(n * 16 + l15) * SPITCH_ + kloc]);
#pragma unroll
        for (int m = 0; m < 4; m++)
#pragma unroll
            for (int n = 0; n < 2; n++)
                acc[m][n] = __builtin_amdgcn_mfma_f32_16x16x32_bf16(
                    afr[m], bfr[n], acc[m][n], 0, 0, 0);
    }

    // ---- epilogue: partial store; kslice 0 carries the bias ----
    float* pb = partb + (size_t)kslice * NPART_;
    const bool addb = (kslice == 0);
#pragma unroll
    for (int m = 0; m < 4; m++)
#pragma unroll
        for (int n = 0; n < 2; n++)
#pragma unroll
            for (int r = 0; r < 4; r++) {
                int oc  = wave * 64 + m * 16 + quad * 4 + r;
                int pix = p0 + n * 16 + l15;
                float v = acc[m][n][r] + (addb ? bconv[oc] : 0.f);
                pb[((size_t)b * CHO_ + oc) * HW_ + pix] = v;
            }
}

// ---------------------------------------------------------------------------
// Kernel 3: BN statistics over the 4 summed partials (deterministic order)
// ---------------------------------------------------------------------------
__global__ __launch_bounds__(256) void bn_stats(
    const float* __restrict__ partb, float* __restrict__ stats)
{
    int o = blockIdx.x, t = threadIdx.x;
    float s = 0.f, s2 = 0.f;
    for (int b = 0; b < BN_; b++) {
        size_t base = ((size_t)b * CHO_ + o) * HW_;
        for (int p = t; p < HW_; p += 256) {
            float v = partb[base + p] + partb[NPART_ + base + p]
                    + partb[2 * NPART_ + base + p] + partb[3 * NPART_ + base + p];
            s += v; s2 += v * v;
        }
    }
#pragma unroll
    for (int off = 32; off > 0; off >>= 1) {
        s  += __shfl_down(s,  off, 64);
        s2 += __shfl_down(s2, off, 64);
    }
    __shared__ float rs[4], rs2[4];
    int lane = t & 63, wv = t >> 6;
    if (lane == 0) { rs[wv] = s; rs2[wv] = s2; }
    __syncthreads();
    if (t == 0) {
        stats[o]        = rs[0] + rs[1] + rs[2] + rs[3];
        stats[CHO_ + o] = rs2[0] + rs2[1] + rs2[2] + rs2[3];
    }
}

// ---------------------------------------------------------------------------
// Kernel 4: BN apply + ReLU from summed partials
// ---------------------------------------------------------------------------
__global__ __launch_bounds__(256) void bn_apply(
    const float* __restrict__ partb, const float* __restrict__ stats,
    const float* __restrict__ gamma, const float* __restrict__ beta,
    float* __restrict__ y)
{
    int idx = blockIdx.x * 256 + threadIdx.x;
    size_t i0 = (size_t)idx * 4;
    int o = (int)((i0 / HW_) % CHO_);
    float4 v0 = *reinterpret_cast<const float4*>(partb + i0);
    float4 v1 = *reinterpret_cast<const float4*>(partb + NPART_ + i0);
    float4 v2 = *reinterpret_cast<const float4*>(partb + 2 * NPART_ + i0);
    float4 v3 = *reinterpret_cast<const float4*>(partb + 3 * NPART_ + i0);
    float4 v;
    v.x = v0.x + v1.x + v2.x + v3.x;
    v.y = v0.y + v1.y + v2.y + v3.y;
    v.z = v0.z + v1.z + v2.z + v3.z;
    v.w = v0.w + v1.w + v2.w + v3.w;
    const float invN = 1.f / (float)NRED_;
    float mu  = stats[o] * invN;
    float var = stats[CHO_ + o] * invN - mu * mu;
    float inv = rsqrtf(var + BN_EPS_);
    float sc = gamma[o] * inv;
    float sh = beta[o] - mu * sc;
    float4 r;
    r.x = fmaxf(v.x * sc + sh, 0.f);
    r.y = fmaxf(v.y * sc + sh, 0.f);
    r.z = fmaxf(v.z * sc + sh, 0.f);
    r.w = fmaxf(v.w * sc + sh, 0.f);
    *reinterpret_cast<float4*>(y + i0) = r;
}

// ---------------------------------------------------------------------------
extern "C" void kernel_launch(void* const* d_in, const int* in_sizes, int n_in,
                              void* d_out, int out_size, void* d_ws, size_t ws_size,
                              hipStream_t stream)
{
    const float* x   = (const float*)d_in[0];
    const float* wof = (const float*)d_in[1];
    const float* bof = (const float*)d_in[2];
    const float* wcv = (const float*)d_in[3];
    const float* bcv = (const float*)d_in[4];
    const float* gam = (const float*)d_in[5];
    const float* bet = (const float*)d_in[6];
    float* y = (float*)d_out;

    char* ws = (char*)d_ws;
    float*          om    = (float*)ws;                                   // 3.98 MB
    float*          stats = (float*)(ws + (size_t)40 * 1024 * 1024);      // 2 KB
    unsigned short* wbf   = (unsigned short*)(ws + (size_t)40 * 1024 * 1024 + 8192);
    unsigned short* wob   = (unsigned short*)(ws + (size_t)40 * 1024 * 1024 + 8192 + 1179648);
    float*          partb = (float*)(ws + (size_t)48 * 1024 * 1024);      // 4 x 36 MB

    w2b<<<(CHO_ * CK_) / 256, 256, 0, stream>>>(wcv, wbf);
    w2b<<<(27 * CK_) / 256, 256, 0, stream>>>(wof, wob);
    offset_mfma<<<BN_ * (HW_ / TPX_), 256, 0, stream>>>(x, wob, bof, om);
    deform_part<<<BN_ * (HW_ / SPX_) * KSPL_, 256, 0, stream>>>(x, om, wbf, bcv, partb);
    bn_stats<<<CHO_, 256, 0, stream>>>(partb, stats);
    bn_apply<<<(BN_ * CHO_ * HW_) / (4 * 256), 256, 0, stream>>>(partb, stats, gam, bet, y);
}